// Round 1
// 1255.142 us; speedup vs baseline: 1.1225x; 1.1225x over previous
//
#include <hip/hip_runtime.h>

// CTC prefix beam search, MI355X. One wave per batch element; latency-bound
// serial scan. This revision shortens the per-step dependent chain:
//   (a) threshold anchor = v1_prev + rowmax(t)  (rowmax emitted by softmax
//       kernel as -log(sum)) -- removes the 6-stage vmax butterfly
//   (b) 3 candidate thresholds counted via ballots+SALU popc (no butterfly,
//       retry is free) -- removes 6-12 more dependent shuffle stages
//   (c) survivor compaction via ballot+mbcnt prefix (no same-address LDS
//       atomics, no cntL round-trip)
//   (d) rank-selection (LDS broadcast compare + ds_permute push-by-rank)
//       instead of the 15-stage u64 bitonic sort-32
//   (e) duplicate-prefix merge as a wave-uniform scalar loop over matched
//       beams (<=1 match per beam: active prefixes are distinct) -- removes
//       mmask LDS atomics, 2 barriers, 16 bpermutes and the exp/log fold
// Exactness: selection is still the exact stable top-16 (same pack_key
// tie-break); merged value is bit-identical (single-element logsumexp = the
// value itself). >32-tie register fallback kept verbatim.

#define T_MAX 256
#define BATCH 32
#define NC 64
#define BEAM 16
#define TOPK 4
#define NEG (-1.0e9f)
#define FLTMAX 3.402823466e+38f

typedef unsigned long long u64;
typedef unsigned int u32;

// Matches jnp.logaddexp exactly: max + log1p(exp(-|a-b|))
__device__ __forceinline__ float log_add_exp(float a, float b) {
    float m = fmaxf(a, b);
    float d = fabsf(a - b);
    return m + log1pf(expf(-d));
}

// Wave-uniform lane reads: VALU->SGPR, no DS pipe. Lane may be dynamic
// (SGPR) as long as it is wave-uniform.
__device__ __forceinline__ u32 rdl_u32(u32 v, int sl) {
    return (u32)__builtin_amdgcn_readlane((int)v, sl);
}
__device__ __forceinline__ float rdl_f(float v, int sl) {
    return __uint_as_float(rdl_u32(__float_as_uint(v), sl));
}
__device__ __forceinline__ int rdl_i(int v, int sl) {
    return __builtin_amdgcn_readlane(v, sl);
}
// popcount of 64-bit mask strictly below this lane
__device__ __forceinline__ u32 mbcnt64(u64 m) {
    return __builtin_amdgcn_mbcnt_hi((u32)(m >> 32),
           __builtin_amdgcn_mbcnt_lo((u32)m, 0u));
}

// u64 key: monotone float in [42:11], (2047-flat) in [10:0].
// Larger key == (larger value, then smaller flat) -> lax.top_k stable order.
// All real keys > 0, so 0 is a safe null (sinks in descending order).
__device__ __forceinline__ u64 pack_key(float v, int flat) {
    u32 u = __float_as_uint(v);
    u32 k = (u & 0x80000000u) ? ~u : (u | 0x80000000u);
    return ((u64)k << 11) | (u64)(2047 - flat);
}
__device__ __forceinline__ float key_val(u64 key) {
    u32 k = (u32)(key >> 11);
    u32 u = (k & 0x80000000u) ? (k ^ 0x80000000u) : ~k;
    return __uint_as_float(u);
}
__device__ __forceinline__ int key_flat(u64 key) {
    return 2047 - (int)(key & 2047u);
}
__device__ __forceinline__ u64 max64(u64 a, u64 b) { return a > b ? a : b; }
__device__ __forceinline__ u64 min64(u64 a, u64 b) { return a < b ? a : b; }

// Bitonic sort of 16 register-resident u64 keys, descending (overflow fallback).
__device__ __forceinline__ void sort16_desc_u64(u64 (&a)[BEAM]) {
    #pragma unroll
    for (int k = 2; k <= 16; k <<= 1) {
        #pragma unroll
        for (int j = k >> 1; j > 0; j >>= 1) {
            #pragma unroll
            for (int i = 0; i < 16; ++i) {
                int l = i ^ j;
                if (l > i) {
                    const bool desc = ((i & k) == 0);
                    u64 x = a[i], y = a[l];
                    bool sw = desc ? (x < y) : (x > y);
                    a[i] = sw ? y : x;
                    a[l] = sw ? x : y;
                }
            }
        }
    }
}

// Bitonic sort of 16 register-resident f32 values, descending.
__device__ __forceinline__ void sort16_desc_f32(float (&a)[BEAM]) {
    #pragma unroll
    for (int k = 2; k <= 16; k <<= 1) {
        #pragma unroll
        for (int j = k >> 1; j > 0; j >>= 1) {
            #pragma unroll
            for (int i = 0; i < 16; ++i) {
                int l = i ^ j;
                if (l > i) {
                    const bool desc = ((i & k) == 0);
                    float x = a[i], y = a[l];
                    float mx = fmaxf(x, y), mn = fminf(x, y);
                    a[i] = desc ? mx : mn;
                    a[l] = desc ? mn : mx;
                }
            }
        }
    }
}

// One value-only butterfly merge level (exact-phase-1 fallback).
template <int M>
__device__ __forceinline__ void bf_level_f32(float (&a)[BEAM]) {
    float c[BEAM];
    #pragma unroll
    for (int i = 0; i < BEAM; ++i)
        c[i] = __shfl_xor(a[BEAM - 1 - i], M, 64);
    #pragma unroll
    for (int i = 0; i < BEAM; ++i)
        c[i] = fmaxf(a[i], c[i]);
    #pragma unroll
    for (int j = 8; j > 0; j >>= 1) {
        #pragma unroll
        for (int i = 0; i < BEAM; ++i)
            if ((i & j) == 0) {
                float x = c[i], y = c[i | j];
                c[i]     = fmaxf(x, y);
                c[i | j] = fminf(x, y);
            }
    }
    #pragma unroll
    for (int i = 0; i < BEAM; ++i) a[i] = c[i];
}

// Fully parallel log-softmax precompute: one 64-lane block per (t,b) row.
// Also emits rowmax = max_c logp = -log(sum) for the beam kernel's anchor.
__global__ __launch_bounds__(64) void softmax_kernel(const float* __restrict__ data,
                                                     float* __restrict__ lp_out,
                                                     float* __restrict__ rm_out) {
    const int row = blockIdx.x;
    const int lane = threadIdx.x;
    float x = data[row * NC + lane];
    float mx = x;
    #pragma unroll
    for (int m = 1; m < 64; m <<= 1) mx = fmaxf(mx, __shfl_xor(mx, m, 64));
    float sum = expf(x - mx);
    #pragma unroll
    for (int m = 1; m < 64; m <<= 1) sum += __shfl_xor(sum, m, 64);
    float ls = logf(sum);
    lp_out[row * NC + lane] = (x - mx) - ls;
    if (lane == 0) rm_out[row] = -ls;
}

template <bool PRE>
__global__ __launch_bounds__(64, 1) void ctc_beam_kernel(
        const float* __restrict__ data,      // [T, B, C] logits
        const float* __restrict__ lp_pre,    // [T, B, C] log-probs (if PRE)
        const float* __restrict__ rm_pre,    // [T, B] row max logp (if PRE)
        const int*   __restrict__ data_len,  // [B]
        float*       __restrict__ out)       // [B*4 probs][B*4 lens][B*4*256 labels]
{
    const int b    = blockIdx.x;
    const int lane = threadIdx.x;

    __shared__ __align__(16) u64 slotsL[64];      // selected-candidate keys
    __shared__ unsigned short hist[T_MAX * BEAM]; // [11:8]=parent, bit7=stay, [6:0]=char
    __shared__ int ord4[TOPK];
    __shared__ float val4[TOPK];

    int len = data_len[b];
    if (len < 0) len = 0;
    if (len > T_MAX) len = T_MAX;

    // ---- beam state in registers (meaningful in lanes < 16) ----
    float pb  = (lane == 0) ? 0.0f : NEG;
    float pnb = NEG;
    u32 h1 = 0u, h2 = 0u;
    int lenb = 0, lastb = -1, actb = (lane == 0) ? 1 : 0;
    float spread = 1.0e30f;   // forces exact path at t=0
    float v1prev = 0.0f;

    const float* src = PRE ? lp_pre : data;
    float xpref = (len > 0) ? src[b * NC + lane] : 0.f;          // prefetch row 0
    float rmpref = (PRE && len > 0) ? rm_pre[b] : 0.f;           // rowmax[0,b]

    #pragma unroll 1
    for (int t = 0; t < len; ++t) {
        float x = xpref;
        float rm = rmpref;
        int tn = (t + 1 < len) ? (t + 1) : t;
        xpref = src[(tn * BATCH + b) * NC + lane];   // prefetch next row early
        if (PRE) rmpref = rm_pre[tn * BATCH + b];

        float lp;
        if (PRE) {
            lp = x;
        } else {
            float mx = x;
            #pragma unroll
            for (int m = 1; m < 64; m <<= 1) mx = fmaxf(mx, __shfl_xor(mx, m, 64));
            float sum = expf(x - mx);
            #pragma unroll
            for (int m = 1; m < 64; m <<= 1) sum += __shfl_xor(sum, m, 64);
            float ls = logf(sum);
            lp = (x - mx) - ls;
            rm = -ls;
        }
        float lp0 = rdl_f(lp, 0);

        // ---- stay candidates (lanes < 16 meaningful) ----
        float tot = log_add_exp(pb, pnb);
        int lastc = (lastb < 0) ? 0 : (lastb & 63);
        float lplast = __shfl(lp, lastc, 64);        // variable lane: bpermute
        float st_pb   = tot + lp0;
        float st_pnb0 = (lenb > 0) ? (pnb + lplast) : NEG;

        u32 actmask = (u32)__ballot(actb != 0) & 0xFFFFu;

        // ---- hash matches via readlane; ACTIVE beams have distinct prefixes,
        //      so each beam j has <=1 matching (parent i, char c) ----
        int mi = -1, mc = 0;
        #pragma unroll
        for (int i = 0; i < BEAM; ++i) {
            u32 h1i = rdl_u32(h1, i);
            u32 h2i = rdl_u32(h2, i);
            u32 c1 = h1 - h1i * 1000003u;
            u32 c2 = h2 - h2i * 69069u;
            if (lane < BEAM && actb && ((actmask >> i) & 1u) &&
                c1 == c2 && (c1 - 1u) <= 63u) { mi = i; mc = (int)c1 - 1; }
        }

        // ---- extend candidates via readlane (lane = class c), no DS ----
        float e0s[BEAM];
        #pragma unroll
        for (int i = 0; i < BEAM; ++i) {
            float tot_i = rdl_f(tot, i);
            float pb_i  = rdl_f(pb, i);
            int  last_i = rdl_i(lastb, i);
            float e0 = ((lane == last_i) ? pb_i : tot_i) + lp;
            if (lane == 0 || !((actmask >> i) & 1u)) e0 = NEG;
            e0s[i] = e0;
        }

        // ---- duplicate-prefix fold: wave-uniform scalar loop over matched
        //      beams. merged_j = ext(i,c) exactly (single-element logsumexp).
        float merged = NEG;
        u32 excl = 0u;
        {
            u64 mm = __ballot(mi >= 0);
            int mpk = (mi << 8) | mc;
            while (mm) {
                int j = __builtin_ctzll(mm);
                mm &= mm - 1;
                int pk = rdl_i(mpk, j);              // dynamic uniform lane
                int i = (pk >> 8) & 15;
                int c = pk & 255;
                float tot_i = rdl_f(tot, i);
                float pb_i  = rdl_f(pb, i);
                int  last_i = rdl_i(lastb, i);
                float lpc   = rdl_f(lp, c);
                float mv = ((c == last_i) ? pb_i : tot_i) + lpc;  // == e0s[i]@lane c
                if (c == 0) mv = NEG;                // blank column is gated NEG
                if (lane == c) excl |= (1u << i);    // exclude ext(i,c)
                if (lane == j && mv > NEG)
                    merged = (merged > NEG) ? log_add_exp(merged, mv) : mv;
            }
        }

        float ev[BEAM];
        #pragma unroll
        for (int s = 0; s < BEAM; ++s)
            ev[s] = ((excl >> s) & 1u) ? NEG : e0s[s];

        float st_pnb = log_add_exp(st_pnb0, merged);
        float st_tot = log_add_exp(st_pb, st_pnb);

        // ---- anchor-based speculative thresholds, counted via ballots.
        //      A >= every pure-extend/stay candidate (up to ~log3 overshoot of
        //      st_tot); exactness is guarded by the count-in-[16,32] check. ----
        float A   = v1prev + rm;
        float th0 = A - spread;                      // primary
        float th1 = A - 0.45f * spread;              // tighter (count>32)
        float th2 = A - (2.5f * spread + 1.0f);      // wider   (count<16)
        u32 cnt0 = 0, cnt1 = 0, cnt2 = 0;
        #pragma unroll
        for (int s = 0; s < BEAM; ++s) {
            float v = ev[s];
            cnt0 += (u32)__popcll(__ballot(v >= th0));
            cnt1 += (u32)__popcll(__ballot(v >= th1));
            cnt2 += (u32)__popcll(__ballot(v >= th2));
        }
        {
            bool stv = (lane < BEAM);
            cnt0 += (u32)__popcll(__ballot(stv && st_tot >= th0));
            cnt1 += (u32)__popcll(__ballot(stv && st_tot >= th1));
            cnt2 += (u32)__popcll(__ballot(stv && st_tot >= th2));
        }

        float thr;
        if      (cnt0 >= BEAM && cnt0 <= 32u) thr = th0;
        else if (cnt1 >= BEAM && cnt1 <= 32u) thr = th1;
        else if (cnt2 >= BEAM && cnt2 <= 32u) thr = th2;
        else {
            // ---- exact phase-1: v16 = 16th-largest of the true multiset ----
            float a[BEAM];
            #pragma unroll
            for (int s = 0; s < BEAM; ++s) a[s] = ev[s];
            sort16_desc_f32(a);
            {   // fold stay value into local sorted list
                float sv = (lane < BEAM) ? st_tot : NEG;
                #pragma unroll
                for (int i = BEAM - 1; i >= 1; --i)
                    a[i] = fmaxf(a[i], fminf(a[i - 1], sv));
                a[0] = fmaxf(a[0], sv);
            }
            bf_level_f32<1>(a);  bf_level_f32<2>(a);  bf_level_f32<4>(a);
            bf_level_f32<8>(a);  bf_level_f32<16>(a); bf_level_f32<32>(a);
            thr = a[15];
        }

        // ---- phase 2: ballot+mbcnt compaction (no LDS atomics), then
        //      rank-selection (no bitonic sort) ----
        int flat; float val;
        {
            u32 basew = 0;
            #pragma unroll
            for (int s = 0; s < BEAM; ++s) {
                u64 bsm = __ballot(ev[s] >= thr);
                u32 pos = basew + mbcnt64(bsm);
                if (ev[s] >= thr && pos < 64u)
                    slotsL[pos] = pack_key(ev[s], BEAM + s * NC + lane);
                basew += (u32)__popcll(bsm);
            }
            {
                u64 bsm = __ballot(lane < BEAM && st_tot >= thr);
                u32 pos = basew + mbcnt64(bsm);
                if (lane < BEAM && st_tot >= thr && pos < 64u)
                    slotsL[pos] = pack_key(st_tot, lane);
                basew += (u32)__popcll(bsm);
            }
            u32 totc = basew;                        // wave-uniform (>=16)

            if (totc <= 32u) {
                if (lane >= (int)totc) slotsL[lane] = 0ull;   // null-pad tail
                __syncthreads();
                u64 mk = slotsL[lane];
                u32 rank = 0;                        // #keys strictly greater
                #pragma unroll
                for (int j = 0; j < 32; ++j)
                    rank += (slotsL[j] > mk) ? 1u : 0u;
                // push-by-rank: lane r receives the rank-r key (ranks unique,
                // keys strictly distinct via flat tie-break)
                int selhi = 0, sello = 0;
                if (lane < (int)totc) {
                    selhi = __builtin_amdgcn_ds_permute((int)(rank << 2),
                                                        (int)(mk >> 32));
                    sello = __builtin_amdgcn_ds_permute((int)(rank << 2),
                                                        (int)(mk & 0xFFFFFFFFu));
                }
                u64 sel = ((u64)(u32)selhi << 32) | (u32)sello;
                flat = key_flat(sel);
                val  = key_val(sel);
            } else {
                // ---- exact u64 register fallback (tie storm), ~never ----
                u64 ku[BEAM];
                #pragma unroll
                for (int s = 0; s < BEAM; ++s)
                    ku[s] = pack_key(ev[s], BEAM + s * NC + lane);
                sort16_desc_u64(ku);
                u64 sk = (lane < BEAM) ? pack_key(st_tot, lane) : 0ull;
                #pragma unroll
                for (int i = BEAM - 1; i >= 1; --i)
                    ku[i] = max64(ku[i], min64(ku[i - 1], sk));
                ku[0] = max64(ku[0], sk);
                #pragma unroll 1
                for (int m = 1; m < 64; m <<= 1) {
                    u64 c_[BEAM];
                    #pragma unroll
                    for (int i = 0; i < BEAM; ++i) {
                        u64 o = (u64)__shfl_xor((long long)ku[BEAM - 1 - i], m, 64);
                        c_[i] = max64(ku[i], o);
                    }
                    #pragma unroll
                    for (int j = 8; j > 0; j >>= 1) {
                        #pragma unroll
                        for (int i = 0; i < BEAM; ++i)
                            if ((i & j) == 0) {
                                u64 xk = c_[i], yk = c_[i | j];
                                bool sw = xk < yk;
                                c_[i]     = sw ? yk : xk;
                                c_[i | j] = sw ? xk : yk;
                            }
                    }
                    #pragma unroll
                    for (int i = 0; i < BEAM; ++i) ku[i] = c_[i];
                }
                u64 selkey = ku[0];
                #pragma unroll
                for (int i = 1; i < BEAM; ++i)
                    if (lane == i) selkey = ku[i];
                flat = key_flat(selkey);
                val  = key_val(selkey);
            }
        }

        // ---- predictor update from the EXACT selection (any path) ----
        {
            float v1n  = rdl_f(val, 0);
            float v16n = rdl_f(val, 15);
            spread = (fmaxf(A, v1n) - v16n) * 1.25f + 1.0e-3f;
            v1prev = v1n;
        }

        // ---- new state (lane k = rank-k winner) ----
        bool stay = flat < BEAM;
        int pidx = stay ? flat : ((flat - BEAM) >> 6);
        pidx &= 15;
        int cnew = stay ? 0 : ((flat - BEAM) & 63);

        // variable-index gathers (bpermute), all independent -> one wait
        float g_stpb  = __shfl(st_pb, pidx, 64);
        float g_stpnb = __shfl(st_pnb, pidx, 64);
        u32   g_h1    = (u32)__shfl((int)h1, pidx, 64);
        u32   g_h2    = (u32)__shfl((int)h2, pidx, 64);
        int   g_ll    = __shfl((lenb << 8) | (lastb & 255), pidx, 64);
        int   g_len   = g_ll >> 8;
        int   g_last  = (int)((signed char)(g_ll & 255));

        pb   = stay ? g_stpb : NEG;
        pnb  = stay ? g_stpnb : val;
        h1   = stay ? g_h1 : (g_h1 * 1000003u + (u32)(cnew + 1));
        h2   = stay ? g_h2 : (g_h2 * 69069u   + (u32)(cnew + 1));
        lenb = g_len + (stay ? 0 : 1);
        lastb = stay ? g_last : cnew;
        actb = (val > -5.0e8f) ? 1 : 0;              // vals > NEG/2
        if (lane < BEAM)
            hist[t * BEAM + lane] =
                (unsigned short)((pidx << 8) | (stay ? 0x80 : 0) | cnew);
    }
    __syncthreads();

    // ---- final stable top-4 over beam totals ----
    float ft = (lane < BEAM) ? log_add_exp(pb, pnb) : -FLTMAX;
    int fidx = (lane < BEAM) ? lane : 0x7FFFFFFF;
    for (int k = 0; k < TOPK; ++k) {
        float bv = ft; int bi = fidx;
        #pragma unroll
        for (int m = 1; m < 64; m <<= 1) {
            float ov = __shfl_xor(bv, m, 64);
            int   oi = __shfl_xor(bi, m, 64);
            if (ov > bv || (ov == bv && oi < bi)) { bv = ov; bi = oi; }
        }
        if (lane == 0) { ord4[k] = bi; val4[k] = bv; }
        if (lane == bi) ft = -FLTMAX;
    }
    __syncthreads();

    int bsel = ord4[lane & 3] & 15;
    int lensel = __shfl(lenb, bsel, 64);

    // ---- outputs: probs [B,4] | lens [B,4] | labels [B,4,256] ----
    for (int e2 = lane; e2 < TOPK * T_MAX; e2 += 64)
        out[BATCH * TOPK * 2 + b * (TOPK * T_MAX) + e2] = -1.0f;
    __syncthreads();
    if (lane < TOPK) {
        const int k = lane;
        out[b * TOPK + k] = -val4[k];
        out[BATCH * TOPK + b * TOPK + k] = (float)lensel;
        int pos = lensel - 1;
        int cur = ord4[k];
        float* lab = out + BATCH * TOPK * 2 + b * (TOPK * T_MAX) + k * T_MAX;
        for (int tt = len - 1; tt >= 0; --tt) {
            unsigned short h = hist[tt * BEAM + cur];
            if (!(h & 0x80)) { lab[pos] = (float)(h & 0x7F); --pos; }
            cur = h >> 8;
        }
    }
}

extern "C" void kernel_launch(void* const* d_in, const int* in_sizes, int n_in,
                              void* d_out, int out_size, void* d_ws, size_t ws_size,
                              hipStream_t stream) {
    const float* data = (const float*)d_in[0];
    const int* data_len = (const int*)d_in[1];
    float* out = (float*)d_out;
    const size_t lp_bytes = (size_t)T_MAX * BATCH * NC * sizeof(float);
    const size_t rm_bytes = (size_t)T_MAX * BATCH * sizeof(float);
    if (ws_size >= lp_bytes + rm_bytes) {
        float* lp_ws = (float*)d_ws;
        float* rm_ws = lp_ws + (size_t)T_MAX * BATCH * NC;
        softmax_kernel<<<dim3(T_MAX * BATCH), dim3(64), 0, stream>>>(data, lp_ws, rm_ws);
        ctc_beam_kernel<true><<<dim3(BATCH), dim3(64), 0, stream>>>(data, lp_ws, rm_ws, data_len, out);
    } else {
        ctc_beam_kernel<false><<<dim3(BATCH), dim3(64), 0, stream>>>(data, nullptr, nullptr, data_len, out);
    }
}

// Round 3
// 1065.663 us; speedup vs baseline: 1.3221x; 1.1778x over previous
//
#include <hip/hip_runtime.h>

// CTC prefix beam search, MI355X. One wave per batch element; latency-bound
// serial scan. R3 = R2 with the rank-loop byte-count bug fixed:
//   q4[q] is 16 BYTES (2 u64 keys); covering 32 keys needs q = 0..15, not
//   0..7. R2 ranked against only slots 0-15 -> duplicate ranks -> ds_permute
//   collisions -> corrupted selection (labels absmax 64).
// R2 changes retained (vs R1):
//   (a) incremental parent-hash (ph1,ph2): merge-target test ph_j == h_i
//       fused into the e0s readlane loop (act_i-gated for inactive-beam
//       stale-hash insurance). Exact: ch(i,c)==h_j <=> h_i==ph_j & c==lastb_j
//       (mod 2^32, both multipliers; difference 2*odd blocks aliasing).
//   (b) branchless merged = ext(mi, lastb) via 3 batched bpermutes; exclusion
//       via 64-entry LDS atomicOr table.
//   (c) threshold th0 counted first (17 ballots); retry only on miss.
//   (d) rank loop reads 32 keys as 16x b128 (FIXED).
//   (e) no in-loop __syncthreads: single wave, in-order same-wave LDS pipe.
// Exactness: selection is the exact stable top-16 (pack_key tie-break =
// lax.top_k order); merged is bit-identical (1-element logsumexp = value).

#define T_MAX 256
#define BATCH 32
#define NC 64
#define BEAM 16
#define TOPK 4
#define NEG (-1.0e9f)
#define FLTMAX 3.402823466e+38f

typedef unsigned long long u64;
typedef unsigned int u32;

// Matches jnp.logaddexp exactly: max + log1p(exp(-|a-b|))
__device__ __forceinline__ float log_add_exp(float a, float b) {
    float m = fmaxf(a, b);
    float d = fabsf(a - b);
    return m + log1pf(expf(-d));
}

// Wave-uniform lane reads: VALU->SGPR, no DS pipe.
__device__ __forceinline__ u32 rdl_u32(u32 v, int sl) {
    return (u32)__builtin_amdgcn_readlane((int)v, sl);
}
__device__ __forceinline__ float rdl_f(float v, int sl) {
    return __uint_as_float(rdl_u32(__float_as_uint(v), sl));
}
__device__ __forceinline__ int rdl_i(int v, int sl) {
    return __builtin_amdgcn_readlane(v, sl);
}
// popcount of 64-bit mask strictly below this lane
__device__ __forceinline__ u32 mbcnt64(u64 m) {
    return __builtin_amdgcn_mbcnt_hi((u32)(m >> 32),
           __builtin_amdgcn_mbcnt_lo((u32)m, 0u));
}

// u64 key: monotone float in [42:11], (2047-flat) in [10:0].
// Larger key == (larger value, then smaller flat) -> lax.top_k stable order.
// All real keys > 0, so 0 is a safe null (sinks in descending order).
__device__ __forceinline__ u64 pack_key(float v, int flat) {
    u32 u = __float_as_uint(v);
    u32 k = (u & 0x80000000u) ? ~u : (u | 0x80000000u);
    return ((u64)k << 11) | (u64)(2047 - flat);
}
__device__ __forceinline__ float key_val(u64 key) {
    u32 k = (u32)(key >> 11);
    u32 u = (k & 0x80000000u) ? (k ^ 0x80000000u) : ~k;
    return __uint_as_float(u);
}
__device__ __forceinline__ int key_flat(u64 key) {
    return 2047 - (int)(key & 2047u);
}
__device__ __forceinline__ u64 max64(u64 a, u64 b) { return a > b ? a : b; }
__device__ __forceinline__ u64 min64(u64 a, u64 b) { return a < b ? a : b; }

// Bitonic sort of 16 register-resident u64 keys, descending (overflow fallback).
__device__ __forceinline__ void sort16_desc_u64(u64 (&a)[BEAM]) {
    #pragma unroll
    for (int k = 2; k <= 16; k <<= 1) {
        #pragma unroll
        for (int j = k >> 1; j > 0; j >>= 1) {
            #pragma unroll
            for (int i = 0; i < 16; ++i) {
                int l = i ^ j;
                if (l > i) {
                    const bool desc = ((i & k) == 0);
                    u64 x = a[i], y = a[l];
                    bool sw = desc ? (x < y) : (x > y);
                    a[i] = sw ? y : x;
                    a[l] = sw ? x : y;
                }
            }
        }
    }
}

// Bitonic sort of 16 register-resident f32 values, descending.
__device__ __forceinline__ void sort16_desc_f32(float (&a)[BEAM]) {
    #pragma unroll
    for (int k = 2; k <= 16; k <<= 1) {
        #pragma unroll
        for (int j = k >> 1; j > 0; j >>= 1) {
            #pragma unroll
            for (int i = 0; i < 16; ++i) {
                int l = i ^ j;
                if (l > i) {
                    const bool desc = ((i & k) == 0);
                    float x = a[i], y = a[l];
                    float mx = fmaxf(x, y), mn = fminf(x, y);
                    a[i] = desc ? mx : mn;
                    a[l] = desc ? mn : mx;
                }
            }
        }
    }
}

// One value-only butterfly merge level (exact-phase-1 fallback).
template <int M>
__device__ __forceinline__ void bf_level_f32(float (&a)[BEAM]) {
    float c[BEAM];
    #pragma unroll
    for (int i = 0; i < BEAM; ++i)
        c[i] = __shfl_xor(a[BEAM - 1 - i], M, 64);
    #pragma unroll
    for (int i = 0; i < BEAM; ++i)
        c[i] = fmaxf(a[i], c[i]);
    #pragma unroll
    for (int j = 8; j > 0; j >>= 1) {
        #pragma unroll
        for (int i = 0; i < BEAM; ++i)
            if ((i & j) == 0) {
                float x = c[i], y = c[i | j];
                c[i]     = fmaxf(x, y);
                c[i | j] = fminf(x, y);
            }
    }
    #pragma unroll
    for (int i = 0; i < BEAM; ++i) a[i] = c[i];
}

// Fully parallel log-softmax precompute: one 64-lane block per (t,b) row.
// Also emits rowmax = max_c logp = -log(sum) for the beam kernel's anchor.
__global__ __launch_bounds__(64) void softmax_kernel(const float* __restrict__ data,
                                                     float* __restrict__ lp_out,
                                                     float* __restrict__ rm_out) {
    const int row = blockIdx.x;
    const int lane = threadIdx.x;
    float x = data[row * NC + lane];
    float mx = x;
    #pragma unroll
    for (int m = 1; m < 64; m <<= 1) mx = fmaxf(mx, __shfl_xor(mx, m, 64));
    float sum = expf(x - mx);
    #pragma unroll
    for (int m = 1; m < 64; m <<= 1) sum += __shfl_xor(sum, m, 64);
    float ls = logf(sum);
    lp_out[row * NC + lane] = (x - mx) - ls;
    if (lane == 0) rm_out[row] = -ls;
}

template <bool PRE>
__global__ __launch_bounds__(64, 1) void ctc_beam_kernel(
        const float* __restrict__ data,      // [T, B, C] logits
        const float* __restrict__ lp_pre,    // [T, B, C] log-probs (if PRE)
        const float* __restrict__ rm_pre,    // [T, B] row max logp (if PRE)
        const int*   __restrict__ data_len,  // [B]
        float*       __restrict__ out)       // [B*4 probs][B*4 lens][B*4*256 labels]
{
    const int b    = blockIdx.x;
    const int lane = threadIdx.x;

    __shared__ __align__(16) u64 slotsL[64];      // selected-candidate keys
    __shared__ u32 tblL[64];                      // per-class exclusion bitmask
    __shared__ unsigned short hist[T_MAX * BEAM]; // [11:8]=parent, bit7=stay, [6:0]=char
    __shared__ int ord4[TOPK];
    __shared__ float val4[TOPK];

    int len = data_len[b];
    if (len < 0) len = 0;
    if (len > T_MAX) len = T_MAX;

    // ---- beam state in registers (meaningful in lanes < 16) ----
    float pb  = (lane == 0) ? 0.0f : NEG;
    float pnb = NEG;
    u32 h1 = 0u, h2 = 0u;        // full prefix hash
    u32 ph1 = 0u, ph2 = 0u;      // hash of prefix minus last char
    int lenb = 0, lastb = -1, actb = (lane == 0) ? 1 : 0;
    float spread = 1.0e30f;      // forces exact path at t=0
    float v1prev = 0.0f;

    const float* src = PRE ? lp_pre : data;
    float xpref = (len > 0) ? src[b * NC + lane] : 0.f;          // prefetch row 0
    float rmpref = (PRE && len > 0) ? rm_pre[b] : 0.f;           // rowmax[0,b]

    #pragma unroll 1
    for (int t = 0; t < len; ++t) {
        float x = xpref;
        float rm = rmpref;
        int tn = (t + 1 < len) ? (t + 1) : t;
        xpref = src[(tn * BATCH + b) * NC + lane];   // prefetch next row early
        if (PRE) rmpref = rm_pre[tn * BATCH + b];

        tblL[lane] = 0u;          // zero exclusion table (in-order DS pipe)

        float lp;
        if (PRE) {
            lp = x;
        } else {
            float mx = x;
            #pragma unroll
            for (int m = 1; m < 64; m <<= 1) mx = fmaxf(mx, __shfl_xor(mx, m, 64));
            float sum = expf(x - mx);
            #pragma unroll
            for (int m = 1; m < 64; m <<= 1) sum += __shfl_xor(sum, m, 64);
            float ls = logf(sum);
            lp = (x - mx) - ls;
            rm = -ls;
        }
        float lp0 = rdl_f(lp, 0);

        // ---- stay candidates (lanes < 16 meaningful) ----
        float tot = log_add_exp(pb, pnb);
        int lastc = (lastb < 0) ? 0 : (lastb & 63);
        float lplast = __shfl(lp, lastc, 64);        // variable lane: bpermute
        float st_pb   = tot + lp0;
        float st_pnb0 = (lenb > 0) ? (pnb + lplast) : NEG;

        int meta = (lastb & 0xFF) | (actb << 8);

        // ---- fused per-beam loop: extends + parent-hash match.
        //      mi = ACTIVE beam i whose FULL hash equals my parent-hash -> my
        //      prefix equals prefix_i + lastb (== reference's ch(i,c)==h(j)). ----
        float e0s[BEAM];
        int mi = -1;
        #pragma unroll
        for (int i = 0; i < BEAM; ++i) {
            float tot_i = rdl_f(tot, i);
            float pb_i  = rdl_f(pb, i);
            int   m_i   = rdl_i(meta, i);
            u32   h1_i  = rdl_u32(h1, i);
            u32   h2_i  = rdl_u32(h2, i);
            int last_i = (int)(signed char)(m_i & 255);
            int act_i  = (m_i >> 8) & 1;
            float e0 = ((lane == last_i) ? pb_i : tot_i) + lp;
            if (lane == 0 || !act_i) e0 = NEG;
            e0s[i] = e0;
            if (act_i && ph1 == h1_i && ph2 == h2_i) mi = i;
        }
        bool jm = (lane < BEAM) && actb && (lenb > 0) && (mi >= 0);
        if (jm) atomicOr(&tblL[lastb & 63], 1u << (mi & 15));

        // ---- merged = ext(mi, lastb), branchless (single-element logsumexp
        //      == the value itself, bit-exact) ----
        int mim = mi & 15;
        float pb_p   = __shfl(pb, mim, 64);
        float tot_p  = __shfl(tot, mim, 64);
        int   meta_p = __shfl(meta, mim, 64);
        int last_p = (int)(signed char)(meta_p & 255);
        int act_p  = (meta_p >> 8) & 1;
        float mvv = ((lastb == last_p) ? pb_p : tot_p) + lplast;
        float merged = (jm && act_p) ? mvv : NEG;

        asm volatile("" ::: "memory");   // order tbl atomics before read
        u32 myx = tblL[lane];            // exclusion bits for my class
        float ev[BEAM];
        #pragma unroll
        for (int s = 0; s < BEAM; ++s)
            ev[s] = ((myx >> s) & 1u) ? NEG : e0s[s];

        float st_pnb = log_add_exp(st_pnb0, merged);
        float st_tot = log_add_exp(st_pb, st_pnb);

        // ---- anchor-based speculative threshold; primary count first,
        //      retry set only on miss (wave-uniform branch). Exactness is
        //      guarded by the count-in-[16,32] check. ----
        float A = v1prev + rm;
        float thr;
        bool ok = false;
        {
            float th = A - spread;
            u32 c0 = 0;
            #pragma unroll
            for (int s = 0; s < BEAM; ++s)
                c0 += (u32)__popcll(__ballot(ev[s] >= th));
            c0 += (u32)__popcll(__ballot(lane < BEAM && st_tot >= th));
            if (c0 >= BEAM && c0 <= 32u) { thr = th; ok = true; }
            else {
                float th2 = (c0 > 32u) ? (A - 0.45f * spread)
                                       : (A - (2.5f * spread + 1.0f));
                u32 c2 = 0;
                #pragma unroll
                for (int s = 0; s < BEAM; ++s)
                    c2 += (u32)__popcll(__ballot(ev[s] >= th2));
                c2 += (u32)__popcll(__ballot(lane < BEAM && st_tot >= th2));
                if (c2 >= BEAM && c2 <= 32u) { thr = th2; ok = true; }
            }
        }
        if (!ok) {
            // ---- exact phase-1: v16 = 16th-largest of the true multiset ----
            float a[BEAM];
            #pragma unroll
            for (int s = 0; s < BEAM; ++s) a[s] = ev[s];
            sort16_desc_f32(a);
            {   // fold stay value into local sorted list
                float sv = (lane < BEAM) ? st_tot : NEG;
                #pragma unroll
                for (int i = BEAM - 1; i >= 1; --i)
                    a[i] = fmaxf(a[i], fminf(a[i - 1], sv));
                a[0] = fmaxf(a[0], sv);
            }
            bf_level_f32<1>(a);  bf_level_f32<2>(a);  bf_level_f32<4>(a);
            bf_level_f32<8>(a);  bf_level_f32<16>(a); bf_level_f32<32>(a);
            thr = a[15];
        }

        // ---- phase 2: ballot+mbcnt compaction, then rank-selection ----
        int flat; float val;
        {
            u32 basew = 0;
            #pragma unroll
            for (int s = 0; s < BEAM; ++s) {
                u64 bsm = __ballot(ev[s] >= thr);
                u32 pos = basew + mbcnt64(bsm);
                if (ev[s] >= thr && pos < 64u)
                    slotsL[pos] = pack_key(ev[s], BEAM + s * NC + lane);
                basew += (u32)__popcll(bsm);
            }
            {
                u64 bsm = __ballot(lane < BEAM && st_tot >= thr);
                u32 pos = basew + mbcnt64(bsm);
                if (lane < BEAM && st_tot >= thr && pos < 64u)
                    slotsL[pos] = pack_key(st_tot, lane);
                basew += (u32)__popcll(bsm);
            }
            u32 totc = basew;                        // wave-uniform (>=16)

            if (totc <= 32u) {
                if (lane >= (int)totc) slotsL[lane] = 0ull;   // null-pad tail
                asm volatile("" ::: "memory");   // single wave: in-order LDS
                u64 mk = slotsL[lane];
                u32 rank = 0;                    // #keys strictly greater
                const uint4* q4 = (const uint4*)slotsL;
                #pragma unroll
                for (int q = 0; q < 16; ++q) {   // 32 keys = 16 x 16B (FIXED)
                    uint4 w = q4[q];
                    u64 ka = ((u64)w.y << 32) | w.x;
                    u64 kb = ((u64)w.w << 32) | w.z;
                    rank += (ka > mk) ? 1u : 0u;
                    rank += (kb > mk) ? 1u : 0u;
                }
                // push-by-rank: lane r receives the rank-r key (ranks unique,
                // keys strictly distinct via flat tie-break)
                int selhi = 0, sello = 0;
                if (lane < (int)totc) {
                    selhi = __builtin_amdgcn_ds_permute((int)(rank << 2),
                                                        (int)(mk >> 32));
                    sello = __builtin_amdgcn_ds_permute((int)(rank << 2),
                                                        (int)(mk & 0xFFFFFFFFu));
                }
                u64 sel = ((u64)(u32)selhi << 32) | (u32)sello;
                flat = key_flat(sel);
                val  = key_val(sel);
            } else {
                // ---- exact u64 register fallback (tie storm), ~never ----
                u64 ku[BEAM];
                #pragma unroll
                for (int s = 0; s < BEAM; ++s)
                    ku[s] = pack_key(ev[s], BEAM + s * NC + lane);
                sort16_desc_u64(ku);
                u64 sk = (lane < BEAM) ? pack_key(st_tot, lane) : 0ull;
                #pragma unroll
                for (int i = BEAM - 1; i >= 1; --i)
                    ku[i] = max64(ku[i], min64(ku[i - 1], sk));
                ku[0] = max64(ku[0], sk);
                #pragma unroll 1
                for (int m = 1; m < 64; m <<= 1) {
                    u64 c_[BEAM];
                    #pragma unroll
                    for (int i = 0; i < BEAM; ++i) {
                        u64 o = (u64)__shfl_xor((long long)ku[BEAM - 1 - i], m, 64);
                        c_[i] = max64(ku[i], o);
                    }
                    #pragma unroll
                    for (int j = 8; j > 0; j >>= 1) {
                        #pragma unroll
                        for (int i = 0; i < BEAM; ++i)
                            if ((i & j) == 0) {
                                u64 xk = c_[i], yk = c_[i | j];
                                bool sw = xk < yk;
                                c_[i]     = sw ? yk : xk;
                                c_[i | j] = sw ? xk : yk;
                            }
                    }
                    #pragma unroll
                    for (int i = 0; i < BEAM; ++i) ku[i] = c_[i];
                }
                u64 selkey = ku[0];
                #pragma unroll
                for (int i = 1; i < BEAM; ++i)
                    if (lane == i) selkey = ku[i];
                flat = key_flat(selkey);
                val  = key_val(selkey);
            }
        }

        // ---- predictor update from the EXACT selection (any path) ----
        {
            float v1n  = rdl_f(val, 0);
            float v16n = rdl_f(val, 15);
            spread = (fmaxf(A, v1n) - v16n) * 1.25f + 1.0e-3f;
            v1prev = v1n;
        }

        // ---- new state (lane k = rank-k winner) ----
        bool stay = flat < BEAM;
        int pidx = (stay ? flat : ((flat - BEAM) >> 6)) & 15;
        int cnew = stay ? 0 : ((flat - BEAM) & 63);

        // variable-index gathers (bpermute), all independent -> one wait
        float g_stpb  = __shfl(st_pb, pidx, 64);
        float g_stpnb = __shfl(st_pnb, pidx, 64);
        u32   g_h1    = (u32)__shfl((int)h1, pidx, 64);
        u32   g_h2    = (u32)__shfl((int)h2, pidx, 64);
        u32   g_ph1   = (u32)__shfl((int)ph1, pidx, 64);
        u32   g_ph2   = (u32)__shfl((int)ph2, pidx, 64);
        int   g_ll    = __shfl((lenb << 8) | (lastb & 255), pidx, 64);
        int   g_len   = g_ll >> 8;
        int   g_last  = (int)(signed char)(g_ll & 255);

        pb   = stay ? g_stpb : NEG;
        pnb  = stay ? g_stpnb : val;
        ph1  = stay ? g_ph1 : g_h1;      // parent-hash of new prefix
        ph2  = stay ? g_ph2 : g_h2;
        h1   = stay ? g_h1 : (g_h1 * 1000003u + (u32)(cnew + 1));
        h2   = stay ? g_h2 : (g_h2 * 69069u   + (u32)(cnew + 1));
        lenb = g_len + (stay ? 0 : 1);
        lastb = stay ? g_last : cnew;
        actb = (val > -5.0e8f) ? 1 : 0;              // vals > NEG/2
        if (lane < BEAM)
            hist[t * BEAM + lane] =
                (unsigned short)((pidx << 8) | (stay ? 0x80 : 0) | cnew);
    }
    __syncthreads();

    // ---- final stable top-4 over beam totals ----
    float ft = (lane < BEAM) ? log_add_exp(pb, pnb) : -FLTMAX;
    int fidx = (lane < BEAM) ? lane : 0x7FFFFFFF;
    for (int k = 0; k < TOPK; ++k) {
        float bv = ft; int bi = fidx;
        #pragma unroll
        for (int m = 1; m < 64; m <<= 1) {
            float ov = __shfl_xor(bv, m, 64);
            int   oi = __shfl_xor(bi, m, 64);
            if (ov > bv || (ov == bv && oi < bi)) { bv = ov; bi = oi; }
        }
        if (lane == 0) { ord4[k] = bi; val4[k] = bv; }
        if (lane == bi) ft = -FLTMAX;
    }
    __syncthreads();

    int bsel = ord4[lane & 3] & 15;
    int lensel = __shfl(lenb, bsel, 64);

    // ---- outputs: probs [B,4] | lens [B,4] | labels [B,4,256] ----
    for (int e2 = lane; e2 < TOPK * T_MAX; e2 += 64)
        out[BATCH * TOPK * 2 + b * (TOPK * T_MAX) + e2] = -1.0f;
    __syncthreads();
    if (lane < TOPK) {
        const int k = lane;
        out[b * TOPK + k] = -val4[k];
        out[BATCH * TOPK + b * TOPK + k] = (float)lensel;
        int pos = lensel - 1;
        int cur = ord4[k];
        float* lab = out + BATCH * TOPK * 2 + b * (TOPK * T_MAX) + k * T_MAX;
        for (int tt = len - 1; tt >= 0; --tt) {
            unsigned short h = hist[tt * BEAM + cur];
            if (!(h & 0x80)) { lab[pos] = (float)(h & 0x7F); --pos; }
            cur = h >> 8;
        }
    }
}

extern "C" void kernel_launch(void* const* d_in, const int* in_sizes, int n_in,
                              void* d_out, int out_size, void* d_ws, size_t ws_size,
                              hipStream_t stream) {
    const float* data = (const float*)d_in[0];
    const int* data_len = (const int*)d_in[1];
    float* out = (float*)d_out;
    const size_t lp_bytes = (size_t)T_MAX * BATCH * NC * sizeof(float);
    const size_t rm_bytes = (size_t)T_MAX * BATCH * sizeof(float);
    if (ws_size >= lp_bytes + rm_bytes) {
        float* lp_ws = (float*)d_ws;
        float* rm_ws = lp_ws + (size_t)T_MAX * BATCH * NC;
        softmax_kernel<<<dim3(T_MAX * BATCH), dim3(64), 0, stream>>>(data, lp_ws, rm_ws);
        ctc_beam_kernel<true><<<dim3(BATCH), dim3(64), 0, stream>>>(data, lp_ws, rm_ws, data_len, out);
    } else {
        ctc_beam_kernel<false><<<dim3(BATCH), dim3(64), 0, stream>>>(data, nullptr, nullptr, data_len, out);
    }
}

// Round 4
// 872.939 us; speedup vs baseline: 1.6140x; 1.2208x over previous
//
#include <hip/hip_runtime.h>

// CTC prefix beam search, MI355X. One wave per batch element; latency-bound
// serial scan. R4 changes (vs R3):
//   (a) tblL exclusion table + atomicOr + 3-shfl merged gather REMOVED:
//       merges handled by a wave-uniform sparse loop over ballot(jm) bits
//       (avg 0-3 iters), pure readlane/SALU, zero DS waits. When no beam
//       merges (mm==0), the whole block and the lae(st_pnb0, NEG) are
//       skipped (bit-safe: log1p(exp(-1e9))==0 for real values; NEG-slot
//       epsilon differences are output-invisible, as already exploited by
//       R3 which measured absmax 0.0).
//   (b) act machinery removed (provably no inactive beams after t=0; at t=0
//       lenb==0 blocks merges and junk ~-1e9 never enters top-16 of the 64
//       real candidates).
//   (c) per-beam broadcast loop: 4 readlanes/iter (tot, pb, h1, p2 where
//       p2 = h2[25:0] | lastb<<26 -- 58-bit hash, collision ~2^-58), blank
//       gate hoisted into lpx = (lane==0 ? -2e9 : lp). lastb=-1 decodes as
//       63; bit-exact because the empty beam always has tot==pb (pnb=NEG+e).
// Exactness: selection is the exact stable top-16 (pack_key tie-break =
// lax.top_k order); merged is bit-identical (1-element logsumexp = value).

#define T_MAX 256
#define BATCH 32
#define NC 64
#define BEAM 16
#define TOPK 4
#define NEG (-1.0e9f)
#define BIGNEG (-2.0e9f)
#define FLTMAX 3.402823466e+38f

typedef unsigned long long u64;
typedef unsigned int u32;

// Matches jnp.logaddexp exactly: max + log1p(exp(-|a-b|))
__device__ __forceinline__ float log_add_exp(float a, float b) {
    float m = fmaxf(a, b);
    float d = fabsf(a - b);
    return m + log1pf(expf(-d));
}

// Wave-uniform lane reads: VALU->SGPR, no DS pipe. Lane index may be a
// wave-uniform SGPR value.
__device__ __forceinline__ u32 rdl_u32(u32 v, int sl) {
    return (u32)__builtin_amdgcn_readlane((int)v, sl);
}
__device__ __forceinline__ float rdl_f(float v, int sl) {
    return __uint_as_float(rdl_u32(__float_as_uint(v), sl));
}
__device__ __forceinline__ int rdl_i(int v, int sl) {
    return __builtin_amdgcn_readlane(v, sl);
}
// popcount of 64-bit mask strictly below this lane
__device__ __forceinline__ u32 mbcnt64(u64 m) {
    return __builtin_amdgcn_mbcnt_hi((u32)(m >> 32),
           __builtin_amdgcn_mbcnt_lo((u32)m, 0u));
}

// u64 key: monotone float in [42:11], (2047-flat) in [10:0].
// Larger key == (larger value, then smaller flat) -> lax.top_k stable order.
// All real keys > 0, so 0 is a safe null (sinks in descending order).
__device__ __forceinline__ u64 pack_key(float v, int flat) {
    u32 u = __float_as_uint(v);
    u32 k = (u & 0x80000000u) ? ~u : (u | 0x80000000u);
    return ((u64)k << 11) | (u64)(2047 - flat);
}
__device__ __forceinline__ float key_val(u64 key) {
    u32 k = (u32)(key >> 11);
    u32 u = (k & 0x80000000u) ? (k ^ 0x80000000u) : ~k;
    return __uint_as_float(u);
}
__device__ __forceinline__ int key_flat(u64 key) {
    return 2047 - (int)(key & 2047u);
}
__device__ __forceinline__ u64 max64(u64 a, u64 b) { return a > b ? a : b; }
__device__ __forceinline__ u64 min64(u64 a, u64 b) { return a < b ? a : b; }

// Bitonic sort of 16 register-resident u64 keys, descending (overflow fallback).
__device__ __forceinline__ void sort16_desc_u64(u64 (&a)[BEAM]) {
    #pragma unroll
    for (int k = 2; k <= 16; k <<= 1) {
        #pragma unroll
        for (int j = k >> 1; j > 0; j >>= 1) {
            #pragma unroll
            for (int i = 0; i < 16; ++i) {
                int l = i ^ j;
                if (l > i) {
                    const bool desc = ((i & k) == 0);
                    u64 x = a[i], y = a[l];
                    bool sw = desc ? (x < y) : (x > y);
                    a[i] = sw ? y : x;
                    a[l] = sw ? x : y;
                }
            }
        }
    }
}

// Bitonic sort of 16 register-resident f32 values, descending.
__device__ __forceinline__ void sort16_desc_f32(float (&a)[BEAM]) {
    #pragma unroll
    for (int k = 2; k <= 16; k <<= 1) {
        #pragma unroll
        for (int j = k >> 1; j > 0; j >>= 1) {
            #pragma unroll
            for (int i = 0; i < 16; ++i) {
                int l = i ^ j;
                if (l > i) {
                    const bool desc = ((i & k) == 0);
                    float x = a[i], y = a[l];
                    float mx = fmaxf(x, y), mn = fminf(x, y);
                    a[i] = desc ? mx : mn;
                    a[l] = desc ? mn : mx;
                }
            }
        }
    }
}

// One value-only butterfly merge level (exact-phase-1 fallback).
template <int M>
__device__ __forceinline__ void bf_level_f32(float (&a)[BEAM]) {
    float c[BEAM];
    #pragma unroll
    for (int i = 0; i < BEAM; ++i)
        c[i] = __shfl_xor(a[BEAM - 1 - i], M, 64);
    #pragma unroll
    for (int i = 0; i < BEAM; ++i)
        c[i] = fmaxf(a[i], c[i]);
    #pragma unroll
    for (int j = 8; j > 0; j >>= 1) {
        #pragma unroll
        for (int i = 0; i < BEAM; ++i)
            if ((i & j) == 0) {
                float x = c[i], y = c[i | j];
                c[i]     = fmaxf(x, y);
                c[i | j] = fminf(x, y);
            }
    }
    #pragma unroll
    for (int i = 0; i < BEAM; ++i) a[i] = c[i];
}

// Fully parallel log-softmax precompute: one 64-lane block per (t,b) row.
// Also emits rowmax = max_c logp = -log(sum) for the beam kernel's anchor.
__global__ __launch_bounds__(64) void softmax_kernel(const float* __restrict__ data,
                                                     float* __restrict__ lp_out,
                                                     float* __restrict__ rm_out) {
    const int row = blockIdx.x;
    const int lane = threadIdx.x;
    float x = data[row * NC + lane];
    float mx = x;
    #pragma unroll
    for (int m = 1; m < 64; m <<= 1) mx = fmaxf(mx, __shfl_xor(mx, m, 64));
    float sum = expf(x - mx);
    #pragma unroll
    for (int m = 1; m < 64; m <<= 1) sum += __shfl_xor(sum, m, 64);
    float ls = logf(sum);
    lp_out[row * NC + lane] = (x - mx) - ls;
    if (lane == 0) rm_out[row] = -ls;
}

template <bool PRE>
__global__ __launch_bounds__(64, 1) void ctc_beam_kernel(
        const float* __restrict__ data,      // [T, B, C] logits
        const float* __restrict__ lp_pre,    // [T, B, C] log-probs (if PRE)
        const float* __restrict__ rm_pre,    // [T, B] row max logp (if PRE)
        const int*   __restrict__ data_len,  // [B]
        float*       __restrict__ out)       // [B*4 probs][B*4 lens][B*4*256 labels]
{
    const int b    = blockIdx.x;
    const int lane = threadIdx.x;

    __shared__ __align__(16) u64 slotsL[64];      // selected-candidate keys
    __shared__ unsigned short hist[T_MAX * BEAM]; // [11:8]=parent, bit7=stay, [6:0]=char
    __shared__ int ord4[TOPK];
    __shared__ float val4[TOPK];

    int len = data_len[b];
    if (len < 0) len = 0;
    if (len > T_MAX) len = T_MAX;

    // ---- beam state in registers (meaningful in lanes < 16) ----
    float pb  = (lane == 0) ? 0.0f : NEG;
    float pnb = NEG;
    u32 h1 = 0u, h2 = 0u;        // full prefix hash
    u32 ph1 = 0u, ph2 = 0u;      // hash of prefix minus last char
    int lenb = 0, lastb = -1;
    float spread = 1.0e30f;      // forces exact path at t=0
    float v1prev = 0.0f;

    const float* src = PRE ? lp_pre : data;
    float xpref = (len > 0) ? src[b * NC + lane] : 0.f;          // prefetch row 0
    float rmpref = (PRE && len > 0) ? rm_pre[b] : 0.f;           // rowmax[0,b]

    #pragma unroll 1
    for (int t = 0; t < len; ++t) {
        float x = xpref;
        float rm = rmpref;
        int tn = (t + 1 < len) ? (t + 1) : t;
        xpref = src[(tn * BATCH + b) * NC + lane];   // prefetch next row early
        if (PRE) rmpref = rm_pre[tn * BATCH + b];

        float lp;
        if (PRE) {
            lp = x;
        } else {
            float mx = x;
            #pragma unroll
            for (int m = 1; m < 64; m <<= 1) mx = fmaxf(mx, __shfl_xor(mx, m, 64));
            float sum = expf(x - mx);
            #pragma unroll
            for (int m = 1; m < 64; m <<= 1) sum += __shfl_xor(sum, m, 64);
            float ls = logf(sum);
            lp = (x - mx) - ls;
            rm = -ls;
        }
        float lp0 = rdl_f(lp, 0);

        // ---- stay candidates (lanes < 16 meaningful) ----
        float tot = log_add_exp(pb, pnb);
        int lastc = (lastb < 0) ? 0 : (lastb & 63);
        float lplast = __shfl(lp, lastc, 64);        // variable lane: bpermute
        float st_pb   = tot + lp0;
        float st_pnb0 = (lenb > 0) ? (pnb + lplast) : NEG;

        // packed broadcast word: h2 low 26 bits | lastb in [31:26]
        // (58-bit effective hash; lastb=-1 encodes as 63 -- bit-exact safe:
        // the only len-0 beam (empty prefix) has tot==pb bitwise.)
        u32 p2 = (h2 & 0x03FFFFFFu) | ((u32)(lastb & 63) << 26);
        u32 ph2m = ph2 & 0x03FFFFFFu;
        float lpx = (lane == 0) ? BIGNEG : lp;       // blank-ext gate, hoisted

        // ---- fused per-beam loop: extends + parent-hash match.
        //      mi = beam i whose full hash equals my parent-hash -> my prefix
        //      equals prefix_i + lastb (== reference's ch(i,c)==h(j)). ----
        float e0s[BEAM];
        int mi = -1;
        #pragma unroll
        for (int i = 0; i < BEAM; ++i) {
            float tot_i = rdl_f(tot, i);
            float pb_i  = rdl_f(pb, i);
            u32   h1_i  = rdl_u32(h1, i);
            u32   p2_i  = rdl_u32(p2, i);
            int last_i = (int)(p2_i >> 26);
            float e0  = tot_i + lpx;
            float e0f = pb_i + lpx;
            e0s[i] = (lane == last_i) ? e0f : e0;
            if (ph1 == h1_i && ph2m == (p2_i & 0x03FFFFFFu)) mi = i;
        }

        // ---- duplicate-prefix fold: sparse wave-uniform loop over the
        //      merging beams (usually 0-3). Pure readlane/SALU, no DS. ----
        bool jm = (lane < BEAM) && (lenb > 0) && (mi >= 0);
        u64 mm = __ballot(jm);
        float merged = NEG;
        float st_pnb;
        if (mm) {
            u32 excl = 0u;
            int mpack = ((mi & 15) << 6) | (lastb & 63);
            u64 mw = mm;
            while (mw) {
                int j = (int)__builtin_ctzll(mw);
                mw &= mw - 1;
                int pk = rdl_i(mpack, j);            // dynamic uniform lane
                int i  = (pk >> 6) & 15;
                int c  = pk & 63;
                float tot_i = rdl_f(tot, i);
                float pb_i  = rdl_f(pb, i);
                int   l_i   = rdl_i(lastb, i);
                float lp_c  = rdl_f(lp, c);
                float mv = ((c == l_i) ? pb_i : tot_i) + lp_c;  // == e0s[i]@lane c
                if (lane == j) merged = mv;
                if (lane == c) excl |= (1u << i);    // exclude ext(i,c)
            }
            #pragma unroll
            for (int s = 0; s < BEAM; ++s)
                if ((excl >> s) & 1u) e0s[s] = BIGNEG;
            st_pnb = log_add_exp(st_pnb0, merged);
        } else {
            st_pnb = st_pnb0;   // lae(x, NEG) == x bit-exact for real x;
                                // NEG-slot eps-differences are invisible
        }
        float st_tot = log_add_exp(st_pb, st_pnb);

        // ---- anchor-based speculative threshold; primary count first,
        //      retry set only on miss (wave-uniform branch). Exactness is
        //      guarded by the count-in-[16,32] check. ----
        float A = v1prev + rm;
        float thr;
        bool ok = false;
        {
            float th = A - spread;
            u32 c0 = 0;
            #pragma unroll
            for (int s = 0; s < BEAM; ++s)
                c0 += (u32)__popcll(__ballot(e0s[s] >= th));
            c0 += (u32)__popcll(__ballot(lane < BEAM && st_tot >= th));
            if (c0 >= BEAM && c0 <= 32u) { thr = th; ok = true; }
            else {
                float th2 = (c0 > 32u) ? (A - 0.45f * spread)
                                       : (A - (2.5f * spread + 1.0f));
                u32 c2 = 0;
                #pragma unroll
                for (int s = 0; s < BEAM; ++s)
                    c2 += (u32)__popcll(__ballot(e0s[s] >= th2));
                c2 += (u32)__popcll(__ballot(lane < BEAM && st_tot >= th2));
                if (c2 >= BEAM && c2 <= 32u) { thr = th2; ok = true; }
            }
        }
        if (!ok) {
            // ---- exact phase-1: v16 = 16th-largest of the true multiset ----
            float a[BEAM];
            #pragma unroll
            for (int s = 0; s < BEAM; ++s) a[s] = e0s[s];
            sort16_desc_f32(a);
            {   // fold stay value into local sorted list
                float sv = (lane < BEAM) ? st_tot : NEG;
                #pragma unroll
                for (int i = BEAM - 1; i >= 1; --i)
                    a[i] = fmaxf(a[i], fminf(a[i - 1], sv));
                a[0] = fmaxf(a[0], sv);
            }
            bf_level_f32<1>(a);  bf_level_f32<2>(a);  bf_level_f32<4>(a);
            bf_level_f32<8>(a);  bf_level_f32<16>(a); bf_level_f32<32>(a);
            thr = a[15];
        }

        // ---- phase 2: ballot+mbcnt compaction, then rank-selection ----
        int flat; float val;
        {
            u32 basew = 0;
            #pragma unroll
            for (int s = 0; s < BEAM; ++s) {
                u64 bsm = __ballot(e0s[s] >= thr);
                u32 pos = basew + mbcnt64(bsm);
                if (e0s[s] >= thr && pos < 64u)
                    slotsL[pos] = pack_key(e0s[s], BEAM + s * NC + lane);
                basew += (u32)__popcll(bsm);
            }
            {
                u64 bsm = __ballot(lane < BEAM && st_tot >= thr);
                u32 pos = basew + mbcnt64(bsm);
                if (lane < BEAM && st_tot >= thr && pos < 64u)
                    slotsL[pos] = pack_key(st_tot, lane);
                basew += (u32)__popcll(bsm);
            }
            u32 totc = basew;                        // wave-uniform (>=16)

            if (totc <= 32u) {
                if (lane >= (int)totc) slotsL[lane] = 0ull;   // null-pad tail
                asm volatile("" ::: "memory");   // single wave: in-order LDS
                u64 mk = slotsL[lane];
                u32 rank = 0;                    // #keys strictly greater
                const uint4* q4 = (const uint4*)slotsL;
                #pragma unroll
                for (int q = 0; q < 16; ++q) {   // 32 keys = 16 x 16B
                    uint4 w = q4[q];
                    u64 ka = ((u64)w.y << 32) | w.x;
                    u64 kb = ((u64)w.w << 32) | w.z;
                    rank += (ka > mk) ? 1u : 0u;
                    rank += (kb > mk) ? 1u : 0u;
                }
                // push-by-rank: lane r receives the rank-r key (ranks unique,
                // keys strictly distinct via flat tie-break)
                int selhi = 0, sello = 0;
                if (lane < (int)totc) {
                    selhi = __builtin_amdgcn_ds_permute((int)(rank << 2),
                                                        (int)(mk >> 32));
                    sello = __builtin_amdgcn_ds_permute((int)(rank << 2),
                                                        (int)(mk & 0xFFFFFFFFu));
                }
                u64 sel = ((u64)(u32)selhi << 32) | (u32)sello;
                flat = key_flat(sel);
                val  = key_val(sel);
            } else {
                // ---- exact u64 register fallback (tie storm), ~never ----
                u64 ku[BEAM];
                #pragma unroll
                for (int s = 0; s < BEAM; ++s)
                    ku[s] = pack_key(e0s[s], BEAM + s * NC + lane);
                sort16_desc_u64(ku);
                u64 sk = (lane < BEAM) ? pack_key(st_tot, lane) : 0ull;
                #pragma unroll
                for (int i = BEAM - 1; i >= 1; --i)
                    ku[i] = max64(ku[i], min64(ku[i - 1], sk));
                ku[0] = max64(ku[0], sk);
                #pragma unroll 1
                for (int m = 1; m < 64; m <<= 1) {
                    u64 c_[BEAM];
                    #pragma unroll
                    for (int i = 0; i < BEAM; ++i) {
                        u64 o = (u64)__shfl_xor((long long)ku[BEAM - 1 - i], m, 64);
                        c_[i] = max64(ku[i], o);
                    }
                    #pragma unroll
                    for (int j = 8; j > 0; j >>= 1) {
                        #pragma unroll
                        for (int i = 0; i < BEAM; ++i)
                            if ((i & j) == 0) {
                                u64 xk = c_[i], yk = c_[i | j];
                                bool sw = xk < yk;
                                c_[i]     = sw ? yk : xk;
                                c_[i | j] = sw ? xk : yk;
                            }
                    }
                    #pragma unroll
                    for (int i = 0; i < BEAM; ++i) ku[i] = c_[i];
                }
                u64 selkey = ku[0];
                #pragma unroll
                for (int i = 1; i < BEAM; ++i)
                    if (lane == i) selkey = ku[i];
                flat = key_flat(selkey);
                val  = key_val(selkey);
            }
        }

        // ---- predictor update from the EXACT selection (any path) ----
        {
            float v1n  = rdl_f(val, 0);
            float v16n = rdl_f(val, 15);
            spread = (fmaxf(A, v1n) - v16n) * 1.25f + 1.0e-3f;
            v1prev = v1n;
        }

        // ---- new state (lane k = rank-k winner) ----
        bool stay = flat < BEAM;
        int pidx = (stay ? flat : ((flat - BEAM) >> 6)) & 15;
        int cnew = stay ? 0 : ((flat - BEAM) & 63);

        // variable-index gathers (bpermute), all independent -> one wait
        float g_stpb  = __shfl(st_pb, pidx, 64);
        float g_stpnb = __shfl(st_pnb, pidx, 64);
        u32   g_h1    = (u32)__shfl((int)h1, pidx, 64);
        u32   g_h2    = (u32)__shfl((int)h2, pidx, 64);
        u32   g_ph1   = (u32)__shfl((int)ph1, pidx, 64);
        u32   g_ph2   = (u32)__shfl((int)ph2, pidx, 64);
        int   g_ll    = __shfl((lenb << 8) | (lastb & 255), pidx, 64);
        int   g_len   = g_ll >> 8;
        int   g_last  = (int)(signed char)(g_ll & 255);

        pb   = stay ? g_stpb : NEG;
        pnb  = stay ? g_stpnb : val;
        ph1  = stay ? g_ph1 : g_h1;      // parent-hash of new prefix
        ph2  = stay ? g_ph2 : g_h2;
        h1   = stay ? g_h1 : (g_h1 * 1000003u + (u32)(cnew + 1));
        h2   = stay ? g_h2 : (g_h2 * 69069u   + (u32)(cnew + 1));
        lenb = g_len + (stay ? 0 : 1);
        lastb = stay ? g_last : cnew;
        if (lane < BEAM)
            hist[t * BEAM + lane] =
                (unsigned short)((pidx << 8) | (stay ? 0x80 : 0) | cnew);
    }
    __syncthreads();

    // ---- final stable top-4 over beam totals ----
    float ft = (lane < BEAM) ? log_add_exp(pb, pnb) : -FLTMAX;
    int fidx = (lane < BEAM) ? lane : 0x7FFFFFFF;
    for (int k = 0; k < TOPK; ++k) {
        float bv = ft; int bi = fidx;
        #pragma unroll
        for (int m = 1; m < 64; m <<= 1) {
            float ov = __shfl_xor(bv, m, 64);
            int   oi = __shfl_xor(bi, m, 64);
            if (ov > bv || (ov == bv && oi < bi)) { bv = ov; bi = oi; }
        }
        if (lane == 0) { ord4[k] = bi; val4[k] = bv; }
        if (lane == bi) ft = -FLTMAX;
    }
    __syncthreads();

    int bsel = ord4[lane & 3] & 15;
    int lensel = __shfl(lenb, bsel, 64);

    // ---- outputs: probs [B,4] | lens [B,4] | labels [B,4,256] ----
    for (int e2 = lane; e2 < TOPK * T_MAX; e2 += 64)
        out[BATCH * TOPK * 2 + b * (TOPK * T_MAX) + e2] = -1.0f;
    __syncthreads();
    if (lane < TOPK) {
        const int k = lane;
        out[b * TOPK + k] = -val4[k];
        out[BATCH * TOPK + b * TOPK + k] = (float)lensel;
        int pos = lensel - 1;
        int cur = ord4[k];
        float* lab = out + BATCH * TOPK * 2 + b * (TOPK * T_MAX) + k * T_MAX;
        for (int tt = len - 1; tt >= 0; --tt) {
            unsigned short h = hist[tt * BEAM + cur];
            if (!(h & 0x80)) { lab[pos] = (float)(h & 0x7F); --pos; }
            cur = h >> 8;
        }
    }
}

extern "C" void kernel_launch(void* const* d_in, const int* in_sizes, int n_in,
                              void* d_out, int out_size, void* d_ws, size_t ws_size,
                              hipStream_t stream) {
    const float* data = (const float*)d_in[0];
    const int* data_len = (const int*)d_in[1];
    float* out = (float*)d_out;
    const size_t lp_bytes = (size_t)T_MAX * BATCH * NC * sizeof(float);
    const size_t rm_bytes = (size_t)T_MAX * BATCH * sizeof(float);
    if (ws_size >= lp_bytes + rm_bytes) {
        float* lp_ws = (float*)d_ws;
        float* rm_ws = lp_ws + (size_t)T_MAX * BATCH * NC;
        softmax_kernel<<<dim3(T_MAX * BATCH), dim3(64), 0, stream>>>(data, lp_ws, rm_ws);
        ctc_beam_kernel<true><<<dim3(BATCH), dim3(64), 0, stream>>>(data, lp_ws, rm_ws, data_len, out);
    } else {
        ctc_beam_kernel<false><<<dim3(BATCH), dim3(64), 0, stream>>>(data, nullptr, nullptr, data_len, out);
    }
}

// Round 5
// 611.573 us; speedup vs baseline: 2.3037x; 1.4274x over previous
//
#include <hip/hip_runtime.h>

// CTC prefix beam search, MI355X. One wave per batch element; latency-bound
// serial scan. R5 changes (vs R4):
//   (a) tot = val carry: next-step tot == this step's selection value val,
//       bit-exactly (stay: val IS lae(st_pb,st_pnb) = the same computation;
//       extend: lae(NEG, val) == val + log1p(exp(-1e9)) == val + 0). Deletes
//       the per-step lae(pb,pnb) from the inter-step critical path.
//   (b) fused speculative scatter: per-lane survivor count + 5-bit
//       ballot/mbcnt exclusive prefix -> scatter in ONE pass; totc from the
//       inclusive prefix at lane 63. Separate 17-ballot count phase removed;
//       retry (rare) rescatters with the adjusted threshold.
//   (c) dump-slot predication: unconditional ds_write with address steered
//       to sacrificial slot 63 for non-survivors/overflow (pad zeroes it
//       before the rank reads; slot 63 never holds a real key since
//       totc<=32 on the rank path). No exec save/restore per write.
// Exactness: selection is the exact stable top-16 (pack_key tie-break =
// lax.top_k order); merged is bit-identical (1-element logsumexp = value).

#define T_MAX 256
#define BATCH 32
#define NC 64
#define BEAM 16
#define TOPK 4
#define NEG (-1.0e9f)
#define BIGNEG (-2.0e9f)
#define FLTMAX 3.402823466e+38f

typedef unsigned long long u64;
typedef unsigned int u32;

// Matches jnp.logaddexp exactly: max + log1p(exp(-|a-b|))
__device__ __forceinline__ float log_add_exp(float a, float b) {
    float m = fmaxf(a, b);
    float d = fabsf(a - b);
    return m + log1pf(expf(-d));
}

// Wave-uniform lane reads: VALU->SGPR, no DS pipe.
__device__ __forceinline__ u32 rdl_u32(u32 v, int sl) {
    return (u32)__builtin_amdgcn_readlane((int)v, sl);
}
__device__ __forceinline__ float rdl_f(float v, int sl) {
    return __uint_as_float(rdl_u32(__float_as_uint(v), sl));
}
__device__ __forceinline__ int rdl_i(int v, int sl) {
    return __builtin_amdgcn_readlane(v, sl);
}
// popcount of 64-bit mask strictly below this lane
__device__ __forceinline__ u32 mbcnt64(u64 m) {
    return __builtin_amdgcn_mbcnt_hi((u32)(m >> 32),
           __builtin_amdgcn_mbcnt_lo((u32)m, 0u));
}

// u64 key: monotone float in [42:11], fl = 2047-flat in [10:0].
// Larger key == (larger value, then smaller flat) -> lax.top_k stable order.
// All real keys > 0, so 0 is a safe null (sinks in descending order).
__device__ __forceinline__ u64 pack_key_fl(float v, u32 fl) {
    u32 u = __float_as_uint(v);
    u32 m = u ^ ((u32)((int)u >> 31) | 0x80000000u);
    return ((u64)m << 11) | (u64)fl;
}
__device__ __forceinline__ u64 pack_key(float v, int flat) {
    return pack_key_fl(v, (u32)(2047 - flat));
}
__device__ __forceinline__ float key_val(u64 key) {
    u32 k = (u32)(key >> 11);
    u32 u = (k & 0x80000000u) ? (k ^ 0x80000000u) : ~k;
    return __uint_as_float(u);
}
__device__ __forceinline__ int key_flat(u64 key) {
    return 2047 - (int)(key & 2047u);
}
__device__ __forceinline__ u64 max64(u64 a, u64 b) { return a > b ? a : b; }
__device__ __forceinline__ u64 min64(u64 a, u64 b) { return a < b ? a : b; }

// Bitonic sort of 16 register-resident u64 keys, descending (overflow fallback).
__device__ __forceinline__ void sort16_desc_u64(u64 (&a)[BEAM]) {
    #pragma unroll
    for (int k = 2; k <= 16; k <<= 1) {
        #pragma unroll
        for (int j = k >> 1; j > 0; j >>= 1) {
            #pragma unroll
            for (int i = 0; i < 16; ++i) {
                int l = i ^ j;
                if (l > i) {
                    const bool desc = ((i & k) == 0);
                    u64 x = a[i], y = a[l];
                    bool sw = desc ? (x < y) : (x > y);
                    a[i] = sw ? y : x;
                    a[l] = sw ? x : y;
                }
            }
        }
    }
}

// Bitonic sort of 16 register-resident f32 values, descending.
__device__ __forceinline__ void sort16_desc_f32(float (&a)[BEAM]) {
    #pragma unroll
    for (int k = 2; k <= 16; k <<= 1) {
        #pragma unroll
        for (int j = k >> 1; j > 0; j >>= 1) {
            #pragma unroll
            for (int i = 0; i < 16; ++i) {
                int l = i ^ j;
                if (l > i) {
                    const bool desc = ((i & k) == 0);
                    float x = a[i], y = a[l];
                    float mx = fmaxf(x, y), mn = fminf(x, y);
                    a[i] = desc ? mx : mn;
                    a[l] = desc ? mn : mx;
                }
            }
        }
    }
}

// One value-only butterfly merge level (exact-phase-1 fallback).
template <int M>
__device__ __forceinline__ void bf_level_f32(float (&a)[BEAM]) {
    float c[BEAM];
    #pragma unroll
    for (int i = 0; i < BEAM; ++i)
        c[i] = __shfl_xor(a[BEAM - 1 - i], M, 64);
    #pragma unroll
    for (int i = 0; i < BEAM; ++i)
        c[i] = fmaxf(a[i], c[i]);
    #pragma unroll
    for (int j = 8; j > 0; j >>= 1) {
        #pragma unroll
        for (int i = 0; i < BEAM; ++i)
            if ((i & j) == 0) {
                float x = c[i], y = c[i | j];
                c[i]     = fmaxf(x, y);
                c[i | j] = fminf(x, y);
            }
    }
    #pragma unroll
    for (int i = 0; i < BEAM; ++i) a[i] = c[i];
}

// Fully parallel log-softmax precompute: one 64-lane block per (t,b) row.
// Also emits rowmax = max_c logp = -log(sum) for the beam kernel's anchor.
__global__ __launch_bounds__(64) void softmax_kernel(const float* __restrict__ data,
                                                     float* __restrict__ lp_out,
                                                     float* __restrict__ rm_out) {
    const int row = blockIdx.x;
    const int lane = threadIdx.x;
    float x = data[row * NC + lane];
    float mx = x;
    #pragma unroll
    for (int m = 1; m < 64; m <<= 1) mx = fmaxf(mx, __shfl_xor(mx, m, 64));
    float sum = expf(x - mx);
    #pragma unroll
    for (int m = 1; m < 64; m <<= 1) sum += __shfl_xor(sum, m, 64);
    float ls = logf(sum);
    lp_out[row * NC + lane] = (x - mx) - ls;
    if (lane == 0) rm_out[row] = -ls;
}

template <bool PRE>
__global__ __launch_bounds__(64, 1) void ctc_beam_kernel(
        const float* __restrict__ data,      // [T, B, C] logits
        const float* __restrict__ lp_pre,    // [T, B, C] log-probs (if PRE)
        const float* __restrict__ rm_pre,    // [T, B] row max logp (if PRE)
        const int*   __restrict__ data_len,  // [B]
        float*       __restrict__ out)       // [B*4 probs][B*4 lens][B*4*256 labels]
{
    const int b    = blockIdx.x;
    const int lane = threadIdx.x;

    __shared__ __align__(16) u64 slotsL[64];      // selected-candidate keys
    __shared__ unsigned short hist[T_MAX * BEAM]; // [11:8]=parent, bit7=stay, [6:0]=char
    __shared__ int ord4[TOPK];
    __shared__ float val4[TOPK];

    int len = data_len[b];
    if (len < 0) len = 0;
    if (len > T_MAX) len = T_MAX;

    // ---- beam state in registers (meaningful in lanes < 16) ----
    float pb  = (lane == 0) ? 0.0f : NEG;
    float pnb = NEG;
    float tot = log_add_exp(pb, pnb);  // carried; inside loop tot == val (bit-exact)
    u32 h1 = 0u, h2 = 0u;        // full prefix hash
    u32 ph1 = 0u, ph2 = 0u;      // hash of prefix minus last char
    int lenb = 0, lastb = -1;
    float spread = 1.0e30f;      // forces exact path at t=0
    float v1prev = 0.0f;

    const float* src = PRE ? lp_pre : data;
    float xpref = (len > 0) ? src[b * NC + lane] : 0.f;          // prefetch row 0
    float rmpref = (PRE && len > 0) ? rm_pre[b] : 0.f;           // rowmax[0,b]

    #pragma unroll 1
    for (int t = 0; t < len; ++t) {
        float x = xpref;
        float rm = rmpref;
        int tn = (t + 1 < len) ? (t + 1) : t;
        xpref = src[(tn * BATCH + b) * NC + lane];   // prefetch next row early
        if (PRE) rmpref = rm_pre[tn * BATCH + b];

        float lp;
        if (PRE) {
            lp = x;
        } else {
            float mx = x;
            #pragma unroll
            for (int m = 1; m < 64; m <<= 1) mx = fmaxf(mx, __shfl_xor(mx, m, 64));
            float sum = expf(x - mx);
            #pragma unroll
            for (int m = 1; m < 64; m <<= 1) sum += __shfl_xor(sum, m, 64);
            float ls = logf(sum);
            lp = (x - mx) - ls;
            rm = -ls;
        }
        float lp0 = rdl_f(lp, 0);

        // ---- stay candidates (lanes < 16 meaningful) ----
        int lastc = (lastb < 0) ? 0 : (lastb & 63);
        float lplast = __shfl(lp, lastc, 64);        // variable lane: bpermute
        float st_pb   = tot + lp0;
        float st_pnb0 = (lenb > 0) ? (pnb + lplast) : NEG;

        // packed broadcast word: h2 low 26 bits | lastb in [31:26]
        u32 p2 = (h2 & 0x03FFFFFFu) | ((u32)(lastb & 63) << 26);
        u32 ph2m = ph2 & 0x03FFFFFFu;
        float lpx = (lane == 0) ? BIGNEG : lp;       // blank-ext gate, hoisted

        // ---- fused per-beam loop: extends + parent-hash match ----
        float e0s[BEAM];
        int mi = -1;
        #pragma unroll
        for (int i = 0; i < BEAM; ++i) {
            float tot_i = rdl_f(tot, i);
            float pb_i  = rdl_f(pb, i);
            u32   h1_i  = rdl_u32(h1, i);
            u32   p2_i  = rdl_u32(p2, i);
            int last_i = (int)(p2_i >> 26);
            float e0  = tot_i + lpx;
            float e0f = pb_i + lpx;
            e0s[i] = (lane == last_i) ? e0f : e0;
            if (ph1 == h1_i && ph2m == (p2_i & 0x03FFFFFFu)) mi = i;
        }

        // ---- duplicate-prefix fold: sparse wave-uniform loop ----
        bool jm = (lane < BEAM) && (lenb > 0) && (mi >= 0);
        u64 mm = __ballot(jm);
        float merged = NEG;
        float st_pnb;
        if (mm) {
            u32 excl = 0u;
            int mpack = ((mi & 15) << 6) | (lastb & 63);
            u64 mw = mm;
            while (mw) {
                int j = (int)__builtin_ctzll(mw);
                mw &= mw - 1;
                int pk = rdl_i(mpack, j);            // dynamic uniform lane
                int i  = (pk >> 6) & 15;
                int c  = pk & 63;
                float tot_i = rdl_f(tot, i);
                float pb_i  = rdl_f(pb, i);
                int   l_i   = rdl_i(lastb, i);
                float lp_c  = rdl_f(lp, c);
                float mv = ((c == l_i) ? pb_i : tot_i) + lp_c;  // == e0s[i]@lane c
                if (lane == j) merged = mv;
                if (lane == c) excl |= (1u << i);    // exclude ext(i,c)
            }
            #pragma unroll
            for (int s = 0; s < BEAM; ++s)
                if ((excl >> s) & 1u) e0s[s] = BIGNEG;
            st_pnb = log_add_exp(st_pnb0, merged);
        } else {
            st_pnb = st_pnb0;   // lae(x, NEG) == x bit-exact for real x
        }
        float st_tot = log_add_exp(st_pb, st_pnb);

        // ---- fused speculative scatter: count + prefix + scatter, one pass.
        //      Non-survivors/overflow steered to dump slot 63 (later zeroed;
        //      never a real key since totc<=32 on the rank path). ----
        auto do_scatter = [&](float th) -> u32 {
            u32 mycnt = 0;
            #pragma unroll
            for (int s = 0; s < BEAM; ++s) mycnt += (e0s[s] >= th) ? 1u : 0u;
            bool stw = (lane < BEAM) && (st_tot >= th);
            mycnt += stw ? 1u : 0u;
            u32 base = 0;
            #pragma unroll
            for (int k = 0; k < 5; ++k)
                base += mbcnt64(__ballot(((mycnt >> k) & 1u) != 0u)) << k;
            u32 totc = rdl_u32(base + mycnt, 63);
            u32 pos = base;
            u32 fl = 2031u - (u32)lane;          // 2047 - (BEAM + 0*NC + lane)
            #pragma unroll
            for (int s = 0; s < BEAM; ++s) {
                bool w = (e0s[s] >= th);
                u32 mp = pos > 63u ? 63u : pos;
                u32 a  = w ? (mp << 3) : 504u;
                *(u64*)((char*)slotsL + a) = pack_key_fl(e0s[s], fl);
                pos += w ? 1u : 0u;
                fl -= 64u;
            }
            {
                u32 mp = pos > 63u ? 63u : pos;
                u32 a  = stw ? (mp << 3) : 504u;
                *(u64*)((char*)slotsL + a) = pack_key_fl(st_tot, 2047u - (u32)lane);
            }
            return totc;
        };

        float A = v1prev + rm;
        u32 totc = do_scatter(A - spread);
        if (totc < BEAM || totc > 32u) {
            float th2 = (totc > 32u) ? (A - 0.45f * spread)
                                     : (A - (2.5f * spread + 1.0f));
            totc = do_scatter(th2);
            if (totc < BEAM || totc > 32u) {
                // ---- exact phase-1: v16 = 16th-largest of the true multiset ----
                float a[BEAM];
                #pragma unroll
                for (int s = 0; s < BEAM; ++s) a[s] = e0s[s];
                sort16_desc_f32(a);
                {   // fold stay value into local sorted list
                    float sv = (lane < BEAM) ? st_tot : NEG;
                    #pragma unroll
                    for (int i = BEAM - 1; i >= 1; --i)
                        a[i] = fmaxf(a[i], fminf(a[i - 1], sv));
                    a[0] = fmaxf(a[0], sv);
                }
                bf_level_f32<1>(a);  bf_level_f32<2>(a);  bf_level_f32<4>(a);
                bf_level_f32<8>(a);  bf_level_f32<16>(a); bf_level_f32<32>(a);
                totc = do_scatter(a[15]);    // totc >= 16 by construction
            }
        }

        int flat; float val;
        if (totc <= 32u) {
            // pad [totc,64) with null keys; lanes < totc dump a 0 to slot 63
            u32 pa = (lane >= (int)totc) ? ((u32)lane << 3) : 504u;
            *(u64*)((char*)slotsL + pa) = 0ull;
            asm volatile("" ::: "memory");   // single wave: in-order LDS
            u64 mk = slotsL[lane];
            u32 rank = 0;                    // #keys strictly greater
            const uint4* q4 = (const uint4*)slotsL;
            #pragma unroll
            for (int q = 0; q < 16; ++q) {   // 32 keys = 16 x 16B
                uint4 w = q4[q];
                u64 ka = ((u64)w.y << 32) | w.x;
                u64 kb = ((u64)w.w << 32) | w.z;
                rank += (ka > mk) ? 1u : 0u;
                rank += (kb > mk) ? 1u : 0u;
            }
            // push-by-rank: lane r receives the rank-r key (ranks unique,
            // keys strictly distinct via flat tie-break)
            int selhi = 0, sello = 0;
            if (lane < (int)totc) {
                selhi = __builtin_amdgcn_ds_permute((int)(rank << 2),
                                                    (int)(mk >> 32));
                sello = __builtin_amdgcn_ds_permute((int)(rank << 2),
                                                    (int)(mk & 0xFFFFFFFFu));
            }
            u64 sel = ((u64)(u32)selhi << 32) | (u32)sello;
            flat = key_flat(sel);
            val  = key_val(sel);
        } else {
            // ---- exact u64 register fallback (tie storm), ~never ----
            u64 ku[BEAM];
            #pragma unroll
            for (int s = 0; s < BEAM; ++s)
                ku[s] = pack_key(e0s[s], BEAM + s * NC + lane);
            sort16_desc_u64(ku);
            u64 sk = (lane < BEAM) ? pack_key(st_tot, lane) : 0ull;
            #pragma unroll
            for (int i = BEAM - 1; i >= 1; --i)
                ku[i] = max64(ku[i], min64(ku[i - 1], sk));
            ku[0] = max64(ku[0], sk);
            #pragma unroll 1
            for (int m = 1; m < 64; m <<= 1) {
                u64 c_[BEAM];
                #pragma unroll
                for (int i = 0; i < BEAM; ++i) {
                    u64 o = (u64)__shfl_xor((long long)ku[BEAM - 1 - i], m, 64);
                    c_[i] = max64(ku[i], o);
                }
                #pragma unroll
                for (int j = 8; j > 0; j >>= 1) {
                    #pragma unroll
                    for (int i = 0; i < BEAM; ++i)
                        if ((i & j) == 0) {
                            u64 xk = c_[i], yk = c_[i | j];
                            bool sw = xk < yk;
                            c_[i]     = sw ? yk : xk;
                            c_[i | j] = sw ? xk : yk;
                        }
                }
                #pragma unroll
                for (int i = 0; i < BEAM; ++i) ku[i] = c_[i];
            }
            u64 selkey = ku[0];
            #pragma unroll
            for (int i = 1; i < BEAM; ++i)
                if (lane == i) selkey = ku[i];
            flat = key_flat(selkey);
            val  = key_val(selkey);
        }

        // ---- predictor update from the EXACT selection (any path) ----
        {
            float v1n  = rdl_f(val, 0);
            float v16n = rdl_f(val, 15);
            spread = (fmaxf(A, v1n) - v16n) * 1.25f + 1.0e-3f;
            v1prev = v1n;
        }

        // ---- new state (lane k = rank-k winner) ----
        bool stay = flat < BEAM;
        int pidx = (stay ? flat : ((flat - BEAM) >> 6)) & 15;
        int cnew = stay ? 0 : ((flat - BEAM) & 63);

        // variable-index gathers (bpermute), all independent -> one wait
        float g_stpb  = __shfl(st_pb, pidx, 64);
        float g_stpnb = __shfl(st_pnb, pidx, 64);
        u32   g_h1    = (u32)__shfl((int)h1, pidx, 64);
        u32   g_h2    = (u32)__shfl((int)h2, pidx, 64);
        u32   g_ph1   = (u32)__shfl((int)ph1, pidx, 64);
        u32   g_ph2   = (u32)__shfl((int)ph2, pidx, 64);
        int   g_ll    = __shfl((lenb << 8) | (lastb & 255), pidx, 64);
        int   g_len   = g_ll >> 8;
        int   g_last  = (int)(signed char)(g_ll & 255);

        pb   = stay ? g_stpb : NEG;
        pnb  = stay ? g_stpnb : val;
        tot  = val;                      // == lae(pb,pnb) bit-exactly
        ph1  = stay ? g_ph1 : g_h1;      // parent-hash of new prefix
        ph2  = stay ? g_ph2 : g_h2;
        h1   = stay ? g_h1 : (g_h1 * 1000003u + (u32)(cnew + 1));
        h2   = stay ? g_h2 : (g_h2 * 69069u   + (u32)(cnew + 1));
        lenb = g_len + (stay ? 0 : 1);
        lastb = stay ? g_last : cnew;
        if (lane < BEAM)
            hist[t * BEAM + lane] =
                (unsigned short)((pidx << 8) | (stay ? 0x80 : 0) | cnew);
    }
    __syncthreads();

    // ---- final stable top-4 over beam totals ----
    float ft = (lane < BEAM) ? log_add_exp(pb, pnb) : -FLTMAX;
    int fidx = (lane < BEAM) ? lane : 0x7FFFFFFF;
    for (int k = 0; k < TOPK; ++k) {
        float bv = ft; int bi = fidx;
        #pragma unroll
        for (int m = 1; m < 64; m <<= 1) {
            float ov = __shfl_xor(bv, m, 64);
            int   oi = __shfl_xor(bi, m, 64);
            if (ov > bv || (ov == bv && oi < bi)) { bv = ov; bi = oi; }
        }
        if (lane == 0) { ord4[k] = bi; val4[k] = bv; }
        if (lane == bi) ft = -FLTMAX;
    }
    __syncthreads();

    int bsel = ord4[lane & 3] & 15;
    int lensel = __shfl(lenb, bsel, 64);

    // ---- outputs: probs [B,4] | lens [B,4] | labels [B,4,256] ----
    for (int e2 = lane; e2 < TOPK * T_MAX; e2 += 64)
        out[BATCH * TOPK * 2 + b * (TOPK * T_MAX) + e2] = -1.0f;
    __syncthreads();
    if (lane < TOPK) {
        const int k = lane;
        out[b * TOPK + k] = -val4[k];
        out[BATCH * TOPK + b * TOPK + k] = (float)lensel;
        int pos = lensel - 1;
        int cur = ord4[k];
        float* lab = out + BATCH * TOPK * 2 + b * (TOPK * T_MAX) + k * T_MAX;
        for (int tt = len - 1; tt >= 0; --tt) {
            unsigned short h = hist[tt * BEAM + cur];
            if (!(h & 0x80)) { lab[pos] = (float)(h & 0x7F); --pos; }
            cur = h >> 8;
        }
    }
}

extern "C" void kernel_launch(void* const* d_in, const int* in_sizes, int n_in,
                              void* d_out, int out_size, void* d_ws, size_t ws_size,
                              hipStream_t stream) {
    const float* data = (const float*)d_in[0];
    const int* data_len = (const int*)d_in[1];
    float* out = (float*)d_out;
    const size_t lp_bytes = (size_t)T_MAX * BATCH * NC * sizeof(float);
    const size_t rm_bytes = (size_t)T_MAX * BATCH * sizeof(float);
    if (ws_size >= lp_bytes + rm_bytes) {
        float* lp_ws = (float*)d_ws;
        float* rm_ws = lp_ws + (size_t)T_MAX * BATCH * NC;
        softmax_kernel<<<dim3(T_MAX * BATCH), dim3(64), 0, stream>>>(data, lp_ws, rm_ws);
        ctc_beam_kernel<true><<<dim3(BATCH), dim3(64), 0, stream>>>(data, lp_ws, rm_ws, data_len, out);
    } else {
        ctc_beam_kernel<false><<<dim3(BATCH), dim3(64), 0, stream>>>(data, nullptr, nullptr, data_len, out);
    }
}